// Round 4
// baseline (116.813 us; speedup 1.0000x reference)
//
#include <hip/hip_runtime.h>

typedef __bf16 bf16_t;
typedef __bf16 bf16x2 __attribute__((ext_vector_type(2)));
typedef __bf16 bf16x4 __attribute__((ext_vector_type(4)));
typedef __bf16 bf16x8 __attribute__((ext_vector_type(8)));
typedef float  f32x4  __attribute__((ext_vector_type(4)));
typedef float  f32x4u __attribute__((ext_vector_type(4), aligned(4)));
typedef unsigned int u32;

#define MFMA16(a, b, c) __builtin_amdgcn_mfma_f32_16x16x32_bf16((a), (b), (c), 0, 0, 0)

// ---------------- LDS layout (38912 B total) ----------------
// [0, 20480)  : K region — 4 heads x [64][40] bf16, head h at el h*2560.
//               OVERLAID first by x [64][136] bf16 (dies at b1.5), later by
//               att [64][136] bf16 (written after b2.5, once K frags preloaded).
// [20480, 38912): vT region — 4 heads x [32][72] bf16, head h at +h*2304 el.
// Q never goes to LDS (in-register D->Bfrag shuffle).
#define SMEM_BYTES 38912

// Fragment conventions for v_mfma_f32_16x16x32_bf16, D = A*B (verified r0-r3):
//  A (MxK): lane holds A[c0][8g+i], i=0..7 (row-major; M-tile via row offset)
//  B (KxN): lane holds B[8g+i][c0]         (row-major read of B^T)
//  D (MxN): lane reg r holds D[4g+r][c0]

union W8 { u32 u[4]; bf16x8 v; };

__device__ __forceinline__ u32 pack2(float a, float b) {
    union { bf16x2 h; u32 u; } c;
    c.h[0] = (bf16_t)a; c.h[1] = (bf16_t)b;
    return c.u;
}

// D-layout -> A/B-frag redistribution within each 4-lane c0-column.
// Input: wd[j] = packed pair, j = 4*fi' + 2*mt' + p (value rows 16mt'+4g+2p..+1).
// Output frag fi word t comes from src lane g'=2*(g&1)+(t>>1), word j=4*fi+2*(g>>1)+(t&1).
// (identical algebra verified by the r3 P-redistribution)
__device__ __forceinline__ void redist(const u32 wd[8], bf16x8 out[2], bool gl, bool gh) {
    u32 X[8], Y[8], Z[8];
    #pragma unroll
    for (int j = 0; j < 8; ++j) X[j] = __shfl_xor(wd[j], 16);
    #pragma unroll
    for (int j = 0; j < 8; ++j) Y[j] = __shfl_xor(wd[j], 32);
    #pragma unroll
    for (int j = 0; j < 8; ++j) Z[j] = __shfl_xor(X[j], 32);
    #pragma unroll
    for (int fi = 0; fi < 2; ++fi) {
        W8 u;
        #pragma unroll
        for (int t = 0; t < 4; ++t) {
            int j0 = 4 * fi + (t & 1);
            int j1 = j0 + 2;
            u32 lo, hi;
            if (t < 2) { lo = gl ? Z[j0] : wd[j0]; hi = gl ? X[j1] : Y[j1]; }
            else       { lo = gl ? Y[j0] : X[j0];  hi = gl ? wd[j1] : Z[j1]; }
            u.u[t] = gh ? hi : lo;
        }
        out[fi] = u.v;
    }
}

__global__ void wconv_kernel(const float* __restrict__ qw, const float* __restrict__ pw,
                             bf16_t* __restrict__ o) {
    int i = (blockIdx.x * 256 + threadIdx.x) * 4;   // 64*256*4 = 65536
    const float* src = (i < 49152) ? (qw + i) : (pw + (i - 49152));
    float4 f = *(const float4*)src;
    bf16x4 h;
    h[0] = (bf16_t)f.x; h[1] = (bf16_t)f.y; h[2] = (bf16_t)f.z; h[3] = (bf16_t)f.w;
    *(bf16x4*)(o + i) = h;
}

__device__ __forceinline__ bf16x8 ldw(const float* __restrict__ wf,
                                      const bf16_t* __restrict__ wb,
                                      int use_b, int idx) {
    if (use_b) {
        return *(const bf16x8*)(wb + idx);
    } else {
        float4 f0 = *(const float4*)(wf + idx);
        float4 f1 = *(const float4*)(wf + idx + 4);
        bf16x8 r;
        r[0] = (bf16_t)f0.x; r[1] = (bf16_t)f0.y; r[2] = (bf16_t)f0.z; r[3] = (bf16_t)f0.w;
        r[4] = (bf16_t)f1.x; r[5] = (bf16_t)f1.y; r[6] = (bf16_t)f1.z; r[7] = (bf16_t)f1.w;
        return r;
    }
}

__global__ __launch_bounds__(512, 6) void winattn_kernel(
    const float* __restrict__ xg, const float* __restrict__ maskg,
    const float* __restrict__ qwg, const float* __restrict__ qbg,
    const float* __restrict__ pwg, const float* __restrict__ pbg,
    const bf16_t* __restrict__ wqb, const bf16_t* __restrict__ wpb,
    const int use_wbf, const int nW, float* __restrict__ outg)
{
    extern __shared__ char smem[];
    bf16_t* xatt = (bf16_t*)smem;                 // [64][136] x, later att
    bf16_t* kreg = (bf16_t*)smem;                 // K: head h at + h*2560 el
    bf16_t* vreg = (bf16_t*)(smem + 20480);       // vT: head h at + h*2304 el

    const int b    = blockIdx.x;
    const int tid  = threadIdx.x;
    const int w    = tid >> 6;
    const int lane = tid & 63;
    const int g    = lane >> 4;
    const int c0   = lane & 15;
    const int h    = w >> 1;
    const int qh2  = w & 1;
    const bool gl  = (g & 1) != 0, gh = (g & 2) != 0;

    const int qrow  = 32 * h;        // Wq rows for this wave's head
    const int kvrow = 128 + 32 * w;  // Wk rows (w<4) / Wv rows (w>=4)

    // ---- phase 0: stage x (49x128 f32 -> bf16 LDS); prefetch ks=0 weights ----
    {
        const float4* xb = (const float4*)(xg + (long)b * 6272);
        #pragma unroll
        for (int it = 0; it < 3; ++it) {
            int i = tid + it * 512;
            float4 f = xb[i];
            int row = i >> 5, col = (i & 31) << 2;
            bf16x4 hq;
            hq[0] = (bf16_t)f.x; hq[1] = (bf16_t)f.y; hq[2] = (bf16_t)f.z; hq[3] = (bf16_t)f.w;
            *(bf16x4*)(xatt + row * 136 + col) = hq;
        }
        if (tid < 32) {
            int i = tid + 1536;
            float4 f = xb[i];
            int row = i >> 5, col = (i & 31) << 2;
            bf16x4 hq;
            hq[0] = (bf16_t)f.x; hq[1] = (bf16_t)f.y; hq[2] = (bf16_t)f.z; hq[3] = (bf16_t)f.w;
            *(bf16x4*)(xatt + row * 136 + col) = hq;
        }
        unsigned int* z = (unsigned int*)(xatt + 49 * 136);
        for (int i = tid; i < 1020; i += 512) z[i] = 0u;
    }
    __syncthreads();   // b1: x staged

    // ---- QKV pass A: q (own 32x32 quadrant) + k-or-v nt=0 ----
    f32x4 qacc[2][2];   // [ntq][mtq]
    f32x4 kv0[4], kv1[4];
    #pragma unroll
    for (int i = 0; i < 2; ++i)
        #pragma unroll
        for (int j = 0; j < 2; ++j) qacc[i][j] = {0.f, 0.f, 0.f, 0.f};
    #pragma unroll
    for (int mt = 0; mt < 4; ++mt) { kv0[mt] = {0.f, 0.f, 0.f, 0.f}; kv1[mt] = {0.f, 0.f, 0.f, 0.f}; }

    #pragma unroll
    for (int ks = 0; ks < 4; ++ks) {
        bf16x8 wq0 = ldw(qwg, wqb, use_wbf, (qrow + c0) * 128 + 32 * ks + 8 * g);
        bf16x8 wq1 = ldw(qwg, wqb, use_wbf, (qrow + 16 + c0) * 128 + 32 * ks + 8 * g);
        bf16x8 wkv = ldw(qwg, wqb, use_wbf, (kvrow + c0) * 128 + 32 * ks + 8 * g);
        bf16x8 xf[4];
        #pragma unroll
        for (int mt = 0; mt < 4; ++mt)
            xf[mt] = *(const bf16x8*)(xatt + (16 * mt + c0) * 136 + 32 * ks + 8 * g);
        #pragma unroll
        for (int ntq = 0; ntq < 2; ++ntq) {
            qacc[ntq][0] = MFMA16(wq0, xf[2 * qh2 + ntq], qacc[ntq][0]);   // D[dh][tok]
            qacc[ntq][1] = MFMA16(wq1, xf[2 * qh2 + ntq], qacc[ntq][1]);
        }
        if (w < 4) {
            #pragma unroll
            for (int mt = 0; mt < 4; ++mt) kv0[mt] = MFMA16(wkv, xf[mt], kv0[mt]);   // D[o][tok]
        } else {
            #pragma unroll
            for (int mt = 0; mt < 4; ++mt) kv0[mt] = MFMA16(xf[mt], wkv, kv0[mt]);   // D[tok][o]
        }
    }

    // v-wave: scatter vT nt=0 now (vT region disjoint from x)
    if (w >= 4) {
        float bv = qbg[kvrow + c0];
        bf16_t* vt = vreg + (w - 4) * 2304;
        #pragma unroll
        for (int mt = 0; mt < 4; ++mt) {
            bf16x4 t;
            t[0] = (bf16_t)(kv0[mt][0] + bv); t[1] = (bf16_t)(kv0[mt][1] + bv);
            t[2] = (bf16_t)(kv0[mt][2] + bv); t[3] = (bf16_t)(kv0[mt][3] + bv);
            *(bf16x4*)(vt + c0 * 72 + 16 * mt + 4 * g) = t;   // vT[dh=c0][tok]
        }
    }

    // ---- q finalize: bias+scale, pack, in-register redistribution -> qb2 ----
    bf16x8 qb2[2];
    {
        const float qs = 0.17677669529663687f;   // 32^-0.5
        float4 qb40 = *(const float4*)(qbg + qrow + 4 * g);
        float4 qb41 = *(const float4*)(qbg + qrow + 16 + 4 * g);
        u32 wd[8];
        #pragma unroll
        for (int j = 0; j < 8; ++j) {
            int ntq = j >> 2, mtq = (j >> 1) & 1, p = j & 1;
            float b0 = mtq ? qb41[2 * p] : qb40[2 * p];
            float b1 = mtq ? qb41[2 * p + 1] : qb40[2 * p + 1];
            wd[j] = pack2((qacc[ntq][mtq][2 * p] + b0) * qs,
                          (qacc[ntq][mtq][2 * p + 1] + b1) * qs);
        }
        redist(wd, qb2, gl, gh);   // qb2[nt]: lane holds Q[32qh2+16nt+c0][8g+i]
    }

    // ---- QKV pass B: k-or-v nt=1 (re-read xf) ----
    #pragma unroll
    for (int ks = 0; ks < 4; ++ks) {
        bf16x8 wkv = ldw(qwg, wqb, use_wbf, (kvrow + 16 + c0) * 128 + 32 * ks + 8 * g);
        bf16x8 xf[4];
        #pragma unroll
        for (int mt = 0; mt < 4; ++mt)
            xf[mt] = *(const bf16x8*)(xatt + (16 * mt + c0) * 136 + 32 * ks + 8 * g);
        if (w < 4) {
            #pragma unroll
            for (int mt = 0; mt < 4; ++mt) kv1[mt] = MFMA16(wkv, xf[mt], kv1[mt]);
        } else {
            #pragma unroll
            for (int mt = 0; mt < 4; ++mt) kv1[mt] = MFMA16(xf[mt], wkv, kv1[mt]);
        }
    }
    if (w >= 4) {
        float bv = qbg[kvrow + 16 + c0];
        bf16_t* vt = vreg + (w - 4) * 2304;
        #pragma unroll
        for (int mt = 0; mt < 4; ++mt) {
            bf16x4 t;
            t[0] = (bf16_t)(kv1[mt][0] + bv); t[1] = (bf16_t)(kv1[mt][1] + bv);
            t[2] = (bf16_t)(kv1[mt][2] + bv); t[3] = (bf16_t)(kv1[mt][3] + bv);
            *(bf16x4*)(vt + (16 + c0) * 72 + 16 * mt + 4 * g) = t;
        }
    }
    __syncthreads();   // b1.5: all x reads done -> K may overwrite x region

    if (w < 4) {
        float4 kb40 = *(const float4*)(qbg + kvrow + 4 * g);
        float4 kb41 = *(const float4*)(qbg + kvrow + 16 + 4 * g);
        bf16_t* kb = kreg + w * 2560;
        #pragma unroll
        for (int mt = 0; mt < 4; ++mt) {
            int tok = 16 * mt + c0;
            bf16x4 t0, t1;
            t0[0] = (bf16_t)(kv0[mt][0] + kb40.x); t0[1] = (bf16_t)(kv0[mt][1] + kb40.y);
            t0[2] = (bf16_t)(kv0[mt][2] + kb40.z); t0[3] = (bf16_t)(kv0[mt][3] + kb40.w);
            t1[0] = (bf16_t)(kv1[mt][0] + kb41.x); t1[1] = (bf16_t)(kv1[mt][1] + kb41.y);
            t1[2] = (bf16_t)(kv1[mt][2] + kb41.z); t1[3] = (bf16_t)(kv1[mt][3] + kb41.w);
            *(bf16x4*)(kb + tok * 40 + 4 * g)      = t0;    // k[tok][dh], dh=4g+r
            *(bf16x4*)(kb + tok * 40 + 16 + 4 * g) = t1;    // dh=16+4g+r
        }
    }
    __syncthreads();   // b2: K/vT ready

    // ---- preload K fragments, then free K region for att ----
    bf16_t* khead = kreg + h * 2560;
    bf16x8 ka[4];
    #pragma unroll
    for (int mt = 0; mt < 4; ++mt)
        ka[mt] = *(const bf16x8*)(khead + (16 * mt + c0) * 40 + 8 * g);
    __syncthreads();   // b2.5: all K reads done -> att writes allowed

    // ---- attention per 16-token group: QK -> softmax -> redist -> PV -> att ----
    const float* mrow = maskg + (long)(b % nW) * 2401;
    bf16_t* vhead = vreg + h * 2304;

    #pragma unroll
    for (int nt = 0; nt < 2; ++nt) {
        // mask row values for this lane (kv = 16mt+4g+r)
        float mv[16];
        {
            int q  = 32 * qh2 + 16 * nt + c0;
            int qm = q < 49 ? q : 48;
            const float* mr = mrow + qm * 49;
            f32x4u m0 = *(const f32x4u*)(mr + 4 * g);
            f32x4u m1 = *(const f32x4u*)(mr + 16 + 4 * g);
            f32x4u m2 = *(const f32x4u*)(mr + 32 + 4 * g);
            float m48 = mr[48];
            #pragma unroll
            for (int r = 0; r < 4; ++r) { mv[r] = m0[r]; mv[4 + r] = m1[r]; mv[8 + r] = m2[r]; }
            mv[12] = (g == 0) ? m48 : -1e30f;
            mv[13] = -1e30f; mv[14] = -1e30f; mv[15] = -1e30f;
        }

        f32x4 s[4];
        #pragma unroll
        for (int mt = 0; mt < 4; ++mt) s[mt] = {0.f, 0.f, 0.f, 0.f};
        #pragma unroll
        for (int mt = 0; mt < 4; ++mt)
            s[mt] = MFMA16(ka[mt], qb2[nt], s[mt]);   // D[kv][q]

        float lg[16];
        float m = -1e30f;
        #pragma unroll
        for (int mt = 0; mt < 4; ++mt)
            #pragma unroll
            for (int r = 0; r < 4; ++r) {
                float v = s[mt][r] + mv[mt * 4 + r];
                lg[mt * 4 + r] = v;
                m = fmaxf(m, v);
            }
        m = fmaxf(m, __shfl_xor(m, 16));
        m = fmaxf(m, __shfl_xor(m, 32));
        float sum = 0.f;
        #pragma unroll
        for (int i = 0; i < 16; ++i) { float e = __expf(lg[i] - m); lg[i] = e; sum += e; }
        sum += __shfl_xor(sum, 16);
        sum += __shfl_xor(sum, 32);
        float inv = 1.f / sum;

        // pack P and redistribute -> pa[ks]: lane holds P[q=32qh2+16nt+c0][32ks+8g+i]
        u32 wd[8];
        #pragma unroll
        for (int j = 0; j < 8; ++j) {
            int mt = j >> 1, rb = (j & 1) * 2;
            wd[j] = pack2(lg[mt * 4 + rb] * inv, lg[mt * 4 + rb + 1] * inv);
        }
        bf16x8 pa[2];
        redist(wd, pa, gl, gh);

        // PV: D[dh][q] = V^T * P^T  (A = vT frags, B = pa)
        f32x4 oo[2];
        oo[0] = {0.f, 0.f, 0.f, 0.f}; oo[1] = {0.f, 0.f, 0.f, 0.f};
        #pragma unroll
        for (int ks = 0; ks < 2; ++ks) {
            bf16x8 va0 = *(const bf16x8*)(vhead + c0 * 72 + 32 * ks + 8 * g);
            bf16x8 va1 = *(const bf16x8*)(vhead + (16 + c0) * 72 + 32 * ks + 8 * g);
            oo[0] = MFMA16(va0, pa[ks], oo[0]);
            oo[1] = MFMA16(va1, pa[ks], oo[1]);
        }
        int tok = 32 * qh2 + 16 * nt + c0;
        #pragma unroll
        for (int dt = 0; dt < 2; ++dt) {
            bf16x4 t;
            t[0] = (bf16_t)oo[dt][0]; t[1] = (bf16_t)oo[dt][1];
            t[2] = (bf16_t)oo[dt][2]; t[3] = (bf16_t)oo[dt][3];
            *(bf16x4*)(xatt + tok * 136 + 32 * h + 16 * dt + 4 * g) = t;   // att[tok][c]
        }
    }

    // issue proj weight loads before the barrier (in flight across it)
    bf16x8 pwf[4];
    #pragma unroll
    for (int ks = 0; ks < 4; ++ks)
        pwf[ks] = ldw(pwg, wpb, use_wbf, (16 * w + c0) * 128 + 32 * ks + 8 * g);
    float4 pbias4 = *(const float4*)(pbg + 16 * w + 4 * g);
    __syncthreads();   // b3: att complete

    // ---- proj GEMM: D[col][tok] = Wp*att^T; float4 stores ----
    {
        f32x4 acc[4];
        #pragma unroll
        for (int mt = 0; mt < 4; ++mt) acc[mt] = {0.f, 0.f, 0.f, 0.f};
        #pragma unroll
        for (int ks = 0; ks < 4; ++ks) {
            bf16x8 af[4];
            #pragma unroll
            for (int mt = 0; mt < 4; ++mt)
                af[mt] = *(const bf16x8*)(xatt + (16 * mt + c0) * 136 + 32 * ks + 8 * g);
            #pragma unroll
            for (int mt = 0; mt < 4; ++mt)
                acc[mt] = MFMA16(pwf[ks], af[mt], acc[mt]);   // D[col][tok]
        }
        float* ob = outg + (long)b * 6272;
        #pragma unroll
        for (int mt = 0; mt < 4; ++mt) {
            int tok = 16 * mt + c0;
            if (tok < 49) {
                float4 t;
                t.x = acc[mt][0] + pbias4.x;
                t.y = acc[mt][1] + pbias4.y;
                t.z = acc[mt][2] + pbias4.z;
                t.w = acc[mt][3] + pbias4.w;
                *(float4*)(ob + tok * 128 + 16 * w + 4 * g) = t;
            }
        }
    }
}

extern "C" void kernel_launch(void* const* d_in, const int* in_sizes, int n_in,
                              void* d_out, int out_size, void* d_ws, size_t ws_size,
                              hipStream_t stream) {
    const float* xg  = (const float*)d_in[0];
    const float* mg  = (const float*)d_in[1];
    const float* qwg = (const float*)d_in[2];
    const float* qbg = (const float*)d_in[3];
    const float* pwg = (const float*)d_in[4];
    const float* pbg = (const float*)d_in[5];
    float* outg = (float*)d_out;

    const int B  = in_sizes[0] / (49 * 128);   // 2048
    const int nW = in_sizes[1] / (49 * 49);    // 64

    int use_wbf = (d_ws != nullptr && ws_size >= 131072) ? 1 : 0;
    bf16_t* wqb = (bf16_t*)d_ws;
    bf16_t* wpb = use_wbf ? (wqb + 49152) : nullptr;
    if (use_wbf)
        wconv_kernel<<<64, 256, 0, stream>>>(qwg, pwg, wqb);

    winattn_kernel<<<B, 512, SMEM_BYTES, stream>>>(
        xg, mg, qwg, qbg, pwg, pbg, wqb, use_wbf ? wpb : wqb, use_wbf, nW, outg);
}

// Round 5
// 100.008 us; speedup vs baseline: 1.1680x; 1.1680x over previous
//
#include <hip/hip_runtime.h>

typedef __bf16 bf16_t;
typedef __bf16 bf16x2 __attribute__((ext_vector_type(2)));
typedef __bf16 bf16x4 __attribute__((ext_vector_type(4)));
typedef __bf16 bf16x8 __attribute__((ext_vector_type(8)));
typedef float  f32x4  __attribute__((ext_vector_type(4)));
typedef float  f32x4u __attribute__((ext_vector_type(4), aligned(4)));
typedef unsigned int u32;

#define MFMA16(a, b, c) __builtin_amdgcn_mfma_f32_16x16x32_bf16((a), (b), (c), 0, 0, 0)

// ---------------- LDS layout (34816 B, static) ----------------
// [0, 17408)     : x   [64][136] bf16 (row stride 272 B, XOR-swizzled)
// [17408, 34816) : att [64][136] bf16 (same geometry)
// K, V, Q live entirely in registers (4-lane redist) — never in LDS.
#define ROWB 272

// Fragment conventions for v_mfma_f32_16x16x32_bf16, D = A*B (verified r0-r4):
//  A (MxK): lane holds A[c0][8g+i], i=0..7
//  B (KxN): lane holds B[8g+i][c0]
//  D (MxN): lane reg r holds D[4g+r][c0]

union W8 { u32 u[4]; bf16x8 v; };

__device__ __forceinline__ u32 pack2(float a, float b) {
    union { bf16x2 h; u32 u; } c;
    c.h[0] = (bf16_t)a; c.h[1] = (bf16_t)b;
    return c.u;
}

// Swizzled x/att access: byte ^= ((row&7)<<4) spreads the 16-row-tile column
// reads across 8 distinct 16B slots (fixes 8-way start-bank collisions).
__device__ __forceinline__ void st_sw4(char* base, int row, int byteoff, bf16x4 v) {
    *(bf16x4*)(base + row * ROWB + (byteoff ^ ((row & 7) << 4))) = v;
}
__device__ __forceinline__ bf16x8 ld_sw8(const char* base, int row, int byteoff) {
    return *(const bf16x8*)(base + row * ROWB + (byteoff ^ ((row & 7) << 4)));
}

// D-layout -> A/B-frag redistribution within each 4-lane c0-column.
// Input wd[j], j = 4*fi + 2*mt' + p: D-tile (row-tile mt', out-group fi), value
// pair p covering D rows 4g+2p, 4g+2p+1.  Output out[fi]: lane holds
// M[<32 merged rows -> 8g+i>][c0].  (verified r3 P-redist, r4 Q-redist)
__device__ __forceinline__ void redist(const u32 wd[8], bf16x8* out, bool gl, bool gh) {
    u32 X[8], Y[8], Z[8];
    #pragma unroll
    for (int j = 0; j < 8; ++j) X[j] = __shfl_xor(wd[j], 16);
    #pragma unroll
    for (int j = 0; j < 8; ++j) Y[j] = __shfl_xor(wd[j], 32);
    #pragma unroll
    for (int j = 0; j < 8; ++j) Z[j] = __shfl_xor(X[j], 32);
    #pragma unroll
    for (int fi = 0; fi < 2; ++fi) {
        W8 u;
        #pragma unroll
        for (int t = 0; t < 4; ++t) {
            int j0 = 4 * fi + (t & 1);
            int j1 = j0 + 2;
            u32 lo, hi;
            if (t < 2) { lo = gl ? Z[j0] : wd[j0]; hi = gl ? X[j1] : Y[j1]; }
            else       { lo = gl ? Y[j0] : X[j0];  hi = gl ? wd[j1] : Z[j1]; }
            u.u[t] = gh ? hi : lo;
        }
        out[fi] = u.v;
    }
}

__global__ void wconv_kernel(const float* __restrict__ qw, const float* __restrict__ pw,
                             bf16_t* __restrict__ o) {
    int i = (blockIdx.x * 256 + threadIdx.x) * 4;   // 64*256*4 = 65536
    const float* src = (i < 49152) ? (qw + i) : (pw + (i - 49152));
    float4 f = *(const float4*)src;
    bf16x4 h;
    h[0] = (bf16_t)f.x; h[1] = (bf16_t)f.y; h[2] = (bf16_t)f.z; h[3] = (bf16_t)f.w;
    *(bf16x4*)(o + i) = h;
}

__device__ __forceinline__ bf16x8 ldw(const float* __restrict__ wf,
                                      const bf16_t* __restrict__ wb,
                                      int use_b, int idx) {
    if (use_b) {
        return *(const bf16x8*)(wb + idx);
    } else {
        float4 f0 = *(const float4*)(wf + idx);
        float4 f1 = *(const float4*)(wf + idx + 4);
        bf16x8 r;
        r[0] = (bf16_t)f0.x; r[1] = (bf16_t)f0.y; r[2] = (bf16_t)f0.z; r[3] = (bf16_t)f0.w;
        r[4] = (bf16_t)f1.x; r[5] = (bf16_t)f1.y; r[6] = (bf16_t)f1.z; r[7] = (bf16_t)f1.w;
        return r;
    }
}

// One 32-row slab of W @ x^T (rows rowbase..rowbase+31), bias+scale folded,
// redistributed to frags: out[t] = lane holds M[16t+c0][dh 8g+i], t=0..3.
__device__ __forceinline__ void pass_rowmajor(
    const char* xs, const float* wf, const bf16_t* wb, int use_b,
    int rowbase, const float* __restrict__ biasp, float scale,
    int g, int c0, bool gl, bool gh, bf16x8 out[4])
{
    f32x4 acc[2][4];
    #pragma unroll
    for (int d = 0; d < 2; ++d)
        #pragma unroll
        for (int mt = 0; mt < 4; ++mt) acc[d][mt] = {0.f, 0.f, 0.f, 0.f};
    #pragma unroll
    for (int ks = 0; ks < 4; ++ks) {
        bf16x8 w0 = ldw(wf, wb, use_b, (rowbase + c0) * 128 + 32 * ks + 8 * g);
        bf16x8 w1 = ldw(wf, wb, use_b, (rowbase + 16 + c0) * 128 + 32 * ks + 8 * g);
        #pragma unroll
        for (int mt = 0; mt < 4; ++mt) {
            bf16x8 xf = ld_sw8(xs, 16 * mt + c0, (32 * ks + 8 * g) * 2);
            acc[0][mt] = MFMA16(w0, xf, acc[0][mt]);   // D[dh 0-15][tok]
            acc[1][mt] = MFMA16(w1, xf, acc[1][mt]);   // D[dh 16-31][tok]
        }
    }
    float4 b0 = *(const float4*)(biasp + rowbase + 4 * g);
    float4 b1 = *(const float4*)(biasp + rowbase + 16 + 4 * g);
    #pragma unroll
    for (int P = 0; P < 2; ++P) {
        u32 wd[8];
        #pragma unroll
        for (int j = 0; j < 8; ++j) {
            int fi = j >> 2, d = (j >> 1) & 1, p = j & 1;
            float bb0 = d ? b1[2 * p] : b0[2 * p];
            float bb1 = d ? b1[2 * p + 1] : b0[2 * p + 1];
            wd[j] = pack2((acc[d][2 * P + fi][2 * p] + bb0) * scale,
                          (acc[d][2 * P + fi][2 * p + 1] + bb1) * scale);
        }
        redist(wd, out + 2 * P, gl, gh);
    }
}

__global__ __launch_bounds__(256, 4) void winattn_kernel(
    const float* __restrict__ xg, const float* __restrict__ maskg,
    const float* __restrict__ qwg, const float* __restrict__ qbg,
    const float* __restrict__ pwg, const float* __restrict__ pbg,
    const bf16_t* __restrict__ wqb, const bf16_t* __restrict__ wpb,
    const int use_wbf, const int nW, float* __restrict__ outg)
{
    __shared__ char smem[34816];
    char* xs = smem;            // x   [64][136]
    char* as = smem + 17408;    // att [64][136]

    const int b    = blockIdx.x;
    const int tid  = threadIdx.x;
    const int w    = tid >> 6;       // wave 0..3 == head
    const int lane = tid & 63;
    const int g    = lane >> 4;
    const int c0   = lane & 15;
    const bool gl  = (g & 1) != 0, gh = (g & 2) != 0;
    const int h    = w;

    // ---- stage x (49x128 f32 -> bf16 LDS, swizzled); zero rows 49..63 ----
    {
        const float4* xb = (const float4*)(xg + (long)b * 6272);
        #pragma unroll
        for (int it = 0; it < 7; ++it) {
            int i = tid + it * 256;
            if (i < 1568) {
                float4 f = xb[i];
                int row = i >> 5, colb = (i & 31) << 3;
                bf16x4 hq;
                hq[0] = (bf16_t)f.x; hq[1] = (bf16_t)f.y; hq[2] = (bf16_t)f.z; hq[3] = (bf16_t)f.w;
                st_sw4(xs, row, colb, hq);
            }
        }
        #pragma unroll
        for (int it = 0; it < 4; ++it) {        // 15 rows x 64 words = 960
            int i = tid + it * 256;
            if (i < 960) {
                int row = 49 + (i >> 6), byteo = (i & 63) << 2;
                *(u32*)(xs + row * ROWB + (byteo ^ ((row & 7) << 4))) = 0u;
            }
        }
    }
    __syncthreads();   // b1: x staged

    // ---- QKV (all in registers; one head per wave) ----
    const float qs = 0.17677669529663687f;   // 32^-0.5
    bf16x8 qfr[4], ka[4];
    pass_rowmajor(xs, qwg, wqb, use_wbf, 32 * h,       qbg, qs,  g, c0, gl, gh, qfr);
    pass_rowmajor(xs, qwg, wqb, use_wbf, 128 + 32 * h, qbg, 1.f, g, c0, gl, gh, ka);

    // V pass: D[tok][dh] orientation, redist merges tok-tiles -> va[dht][kt]
    bf16x8 va[2][2];
    {
        const int rb = 256 + 32 * h;
        f32x4 acc[4][2];
        #pragma unroll
        for (int mt = 0; mt < 4; ++mt)
            #pragma unroll
            for (int d = 0; d < 2; ++d) acc[mt][d] = {0.f, 0.f, 0.f, 0.f};
        #pragma unroll
        for (int ks = 0; ks < 4; ++ks) {
            bf16x8 w0 = ldw(qwg, wqb, use_wbf, (rb + c0) * 128 + 32 * ks + 8 * g);
            bf16x8 w1 = ldw(qwg, wqb, use_wbf, (rb + 16 + c0) * 128 + 32 * ks + 8 * g);
            #pragma unroll
            for (int mt = 0; mt < 4; ++mt) {
                bf16x8 xf = ld_sw8(xs, 16 * mt + c0, (32 * ks + 8 * g) * 2);
                acc[mt][0] = MFMA16(xf, w0, acc[mt][0]);   // D[tok][dh 0-15]
                acc[mt][1] = MFMA16(xf, w1, acc[mt][1]);   // D[tok][dh 16-31]
            }
        }
        float vb0 = qbg[rb + c0];
        float vb1 = qbg[rb + 16 + c0];
        #pragma unroll
        for (int kt = 0; kt < 2; ++kt) {
            u32 wd[8];
            #pragma unroll
            for (int j = 0; j < 8; ++j) {
                int fi = j >> 2, m2 = (j >> 1) & 1, p = j & 1;
                float bb = fi ? vb1 : vb0;
                wd[j] = pack2(acc[2 * kt + m2][fi][2 * p] + bb,
                              acc[2 * kt + m2][fi][2 * p + 1] + bb);
            }
            bf16x8 tmp[2];
            redist(wd, tmp, gl, gh);
            va[0][kt] = tmp[0];   // vT[c0][32kt+8g+i]
            va[1][kt] = tmp[1];   // vT[16+c0][32kt+8g+i]
        }
    }

    // ---- attention: per 16-q-tile: S^T -> softmax -> redist P -> PV -> att ----
    const float* mrow = maskg + (long)(b % nW) * 2401;
    #pragma unroll
    for (int nt = 0; nt < 4; ++nt) {
        float mv[16];
        {
            int q  = 16 * nt + c0;
            int qm = q < 49 ? q : 48;
            const float* mr = mrow + qm * 49;
            f32x4u m0 = *(const f32x4u*)(mr + 4 * g);
            f32x4u m1 = *(const f32x4u*)(mr + 16 + 4 * g);
            f32x4u m2 = *(const f32x4u*)(mr + 32 + 4 * g);
            float m48 = mr[48];
            #pragma unroll
            for (int r = 0; r < 4; ++r) { mv[r] = m0[r]; mv[4 + r] = m1[r]; mv[8 + r] = m2[r]; }
            mv[12] = (g == 0) ? m48 : -1e30f;
            mv[13] = -1e30f; mv[14] = -1e30f; mv[15] = -1e30f;
        }

        f32x4 s[4];
        #pragma unroll
        for (int kt = 0; kt < 4; ++kt) s[kt] = {0.f, 0.f, 0.f, 0.f};
        #pragma unroll
        for (int kt = 0; kt < 4; ++kt)
            s[kt] = MFMA16(ka[kt], qfr[nt], s[kt]);   // D[kv][q]

        float lg[16];
        float m = -1e30f;
        #pragma unroll
        for (int kt = 0; kt < 4; ++kt)
            #pragma unroll
            for (int r = 0; r < 4; ++r) {
                float v = s[kt][r] + mv[kt * 4 + r];
                lg[kt * 4 + r] = v;
                m = fmaxf(m, v);
            }
        m = fmaxf(m, __shfl_xor(m, 16));
        m = fmaxf(m, __shfl_xor(m, 32));
        float sum = 0.f;
        #pragma unroll
        for (int i = 0; i < 16; ++i) { float e = __expf(lg[i] - m); lg[i] = e; sum += e; }
        sum += __shfl_xor(sum, 16);
        sum += __shfl_xor(sum, 32);
        float inv = 1.f / sum;   // uniform within the 4-lane c0-column

        // P unnormalized -> bf16 pack -> redist; normalize after PV
        u32 wd[8];
        #pragma unroll
        for (int j = 0; j < 8; ++j) {
            int kt = j >> 1, rb2 = (j & 1) * 2;
            wd[j] = pack2(lg[kt * 4 + rb2], lg[kt * 4 + rb2 + 1]);
        }
        bf16x8 pa[2];
        redist(wd, pa, gl, gh);   // pa[kt]: lane holds P[q=16nt+c0][32kt+8g+i]

        f32x4 oo[2];
        oo[0] = {0.f, 0.f, 0.f, 0.f}; oo[1] = {0.f, 0.f, 0.f, 0.f};
        #pragma unroll
        for (int kt = 0; kt < 2; ++kt) {
            oo[0] = MFMA16(va[0][kt], pa[kt], oo[0]);   // D[dh 0-15][q]
            oo[1] = MFMA16(va[1][kt], pa[kt], oo[1]);   // D[dh 16-31][q]
        }
        int q = 16 * nt + c0;
        #pragma unroll
        for (int dt = 0; dt < 2; ++dt) {
            bf16x4 t;
            t[0] = (bf16_t)(oo[dt][0] * inv); t[1] = (bf16_t)(oo[dt][1] * inv);
            t[2] = (bf16_t)(oo[dt][2] * inv); t[3] = (bf16_t)(oo[dt][3] * inv);
            st_sw4(as, q, (32 * h + 16 * dt + 4 * g) * 2, t);   // att[q][c]
        }
    }
    __syncthreads();   // b2: att complete

    // ---- proj GEMM: D[col][tok] = Wp*att^T; wave owns cols 32w..32w+31 ----
    {
        f32x4 acc[2][4];
        #pragma unroll
        for (int nt = 0; nt < 2; ++nt)
            #pragma unroll
            for (int mt = 0; mt < 4; ++mt) acc[nt][mt] = {0.f, 0.f, 0.f, 0.f};
        #pragma unroll
        for (int ks = 0; ks < 4; ++ks) {
            bf16x8 p0 = ldw(pwg, wpb, use_wbf, (32 * w + c0) * 128 + 32 * ks + 8 * g);
            bf16x8 p1 = ldw(pwg, wpb, use_wbf, (32 * w + 16 + c0) * 128 + 32 * ks + 8 * g);
            #pragma unroll
            for (int mt = 0; mt < 4; ++mt) {
                bf16x8 af = ld_sw8(as, 16 * mt + c0, (32 * ks + 8 * g) * 2);
                acc[0][mt] = MFMA16(p0, af, acc[0][mt]);
                acc[1][mt] = MFMA16(p1, af, acc[1][mt]);
            }
        }
        float4 pb0 = *(const float4*)(pbg + 32 * w + 4 * g);
        float4 pb1 = *(const float4*)(pbg + 32 * w + 16 + 4 * g);
        float* ob = outg + (long)b * 6272;
        #pragma unroll
        for (int nt = 0; nt < 2; ++nt) {
            float4 pb = nt ? pb1 : pb0;
            #pragma unroll
            for (int mt = 0; mt < 4; ++mt) {
                int tok = 16 * mt + c0;
                if (tok < 49) {
                    float4 t;
                    t.x = acc[nt][mt][0] + pb.x;
                    t.y = acc[nt][mt][1] + pb.y;
                    t.z = acc[nt][mt][2] + pb.z;
                    t.w = acc[nt][mt][3] + pb.w;
                    *(float4*)(ob + tok * 128 + 32 * w + 16 * nt + 4 * g) = t;
                }
            }
        }
    }
}

extern "C" void kernel_launch(void* const* d_in, const int* in_sizes, int n_in,
                              void* d_out, int out_size, void* d_ws, size_t ws_size,
                              hipStream_t stream) {
    const float* xg  = (const float*)d_in[0];
    const float* mg  = (const float*)d_in[1];
    const float* qwg = (const float*)d_in[2];
    const float* qbg = (const float*)d_in[3];
    const float* pwg = (const float*)d_in[4];
    const float* pbg = (const float*)d_in[5];
    float* outg = (float*)d_out;

    const int B  = in_sizes[0] / (49 * 128);   // 2048
    const int nW = in_sizes[1] / (49 * 49);    // 64

    int use_wbf = (d_ws != nullptr && ws_size >= 131072) ? 1 : 0;
    bf16_t* wqb = (bf16_t*)d_ws;
    bf16_t* wpb = use_wbf ? (wqb + 49152) : nullptr;
    if (use_wbf)
        wconv_kernel<<<64, 256, 0, stream>>>(qwg, pwg, wqb);

    winattn_kernel<<<B, 256, 0, stream>>>(
        xg, mg, qwg, qbg, pwg, pbg, wqb, use_wbf ? wpb : wqb, use_wbf, nW, outg);
}

// Round 6
// 67.365 us; speedup vs baseline: 1.7340x; 1.4846x over previous
//
#include <hip/hip_runtime.h>

typedef __bf16 bf16_t;
typedef __bf16 bf16x2 __attribute__((ext_vector_type(2)));
typedef __bf16 bf16x4 __attribute__((ext_vector_type(4)));
typedef __bf16 bf16x8 __attribute__((ext_vector_type(8)));
typedef float  f32x4  __attribute__((ext_vector_type(4)));
typedef float  f32x4u __attribute__((ext_vector_type(4), aligned(4)));
typedef unsigned int u32;

#define MFMA16(a, b, c) __builtin_amdgcn_mfma_f32_16x16x32_bf16((a), (b), (c), 0, 0, 0)

// ---------------- LDS: ONE region, 17408 B ----------------
// [64][136] bf16, row stride 272 B. Holds x until the V pass, then att.
// ROWB=272 gives a natural +16B/row stagger (272 mod 128 = 16): a 16-row
// column read of 16B/lane covers 8 distinct 16B slots -> 2-way = free.
// NO additional XOR swizzle (it would cancel the stagger - r5 lesson).
#define ROWB 272

// Fragment conventions for v_mfma_f32_16x16x32_bf16, D = A*B (verified r0-r5):
//  A (MxK): lane holds A[c0][8g+i], i=0..7
//  B (KxN): lane holds B[8g+i][c0]
//  D (MxN): lane reg r holds D[4g+r][c0]

union W8 { u32 u[4]; bf16x8 v; };

__device__ __forceinline__ u32 pack2(float a, float b) {
    union { bf16x2 h; u32 u; } c;
    c.h[0] = (bf16_t)a; c.h[1] = (bf16_t)b;
    return c.u;
}

__device__ __forceinline__ void st4(char* base, int row, int byteoff, bf16x4 v) {
    *(bf16x4*)(base + row * ROWB + byteoff) = v;
}
__device__ __forceinline__ bf16x8 ld8(const char* base, int row, int byteoff) {
    return *(const bf16x8*)(base + row * ROWB + byteoff);
}

// D-layout -> A/B-frag redistribution within each 4-lane c0-column.
// Input wd[j], j = 2*u + p: merge-tile u (two 16-row D tiles being merged into
// one 32-deep frag dim), pair p covering D rows 4g+2p, 4g+2p+1.
// Output: lane holds M[row][8g+i] merged dim. (algebra verified r3/r4/r5)
__device__ __forceinline__ bf16x8 redist4(u32 w0, u32 w1, u32 w2, u32 w3,
                                          bool gl, bool gh) {
    u32 wd[4] = {w0, w1, w2, w3};
    u32 X[4], Y[4], Z[4];
    #pragma unroll
    for (int j = 0; j < 4; ++j) X[j] = __shfl_xor(wd[j], 16);
    #pragma unroll
    for (int j = 0; j < 4; ++j) Y[j] = __shfl_xor(wd[j], 32);
    #pragma unroll
    for (int j = 0; j < 4; ++j) Z[j] = __shfl_xor(X[j], 32);
    W8 u;
    #pragma unroll
    for (int t = 0; t < 4; ++t) {
        int j0 = t & 1;
        int j1 = j0 + 2;
        u32 lo, hi;
        if (t < 2) { lo = gl ? Z[j0] : wd[j0]; hi = gl ? X[j1] : Y[j1]; }
        else       { lo = gl ? Y[j0] : X[j0];  hi = gl ? wd[j1] : Z[j1]; }
        u.u[t] = gh ? hi : lo;
    }
    return u.v;
}

__global__ void wconv_kernel(const float* __restrict__ qw, const float* __restrict__ pw,
                             bf16_t* __restrict__ o) {
    int i = (blockIdx.x * 256 + threadIdx.x) * 4;   // 64*256*4 = 65536
    const float* src = (i < 49152) ? (qw + i) : (pw + (i - 49152));
    float4 f = *(const float4*)src;
    bf16x4 h;
    h[0] = (bf16_t)f.x; h[1] = (bf16_t)f.y; h[2] = (bf16_t)f.z; h[3] = (bf16_t)f.w;
    *(bf16x4*)(o + i) = h;
}

template<int USEB>
__device__ __forceinline__ bf16x8 ldw(const float* __restrict__ wf,
                                      const bf16_t* __restrict__ wb, int idx) {
    if constexpr (USEB) {
        return *(const bf16x8*)(wb + idx);
    } else {
        float4 f0 = *(const float4*)(wf + idx);
        float4 f1 = *(const float4*)(wf + idx + 4);
        bf16x8 r;
        r[0] = (bf16_t)f0.x; r[1] = (bf16_t)f0.y; r[2] = (bf16_t)f0.z; r[3] = (bf16_t)f0.w;
        r[4] = (bf16_t)f1.x; r[5] = (bf16_t)f1.y; r[6] = (bf16_t)f1.z; r[7] = (bf16_t)f1.w;
        return r;
    }
}

// One 32-row slab of W @ x^T (rows rowbase..+31), bias+scale folded, frags out:
// out[t] = lane holds M[16t+c0][dh 8g+i] (A-frag for row-tile t).
template<int USEB>
__device__ __forceinline__ void pass_rowmajor(
    const char* xs, const float* __restrict__ wf, const bf16_t* __restrict__ wb,
    int rowbase, const float* __restrict__ biasp, float scale,
    int g, int c0, bool gl, bool gh, bf16x8 out[4])
{
    f32x4 acc[2][4];
    #pragma unroll
    for (int d = 0; d < 2; ++d)
        #pragma unroll
        for (int mt = 0; mt < 4; ++mt) acc[d][mt] = {0.f, 0.f, 0.f, 0.f};
    #pragma unroll
    for (int ks = 0; ks < 4; ++ks) {
        bf16x8 w0 = ldw<USEB>(wf, wb, (rowbase + c0) * 128 + 32 * ks + 8 * g);
        bf16x8 w1 = ldw<USEB>(wf, wb, (rowbase + 16 + c0) * 128 + 32 * ks + 8 * g);
        #pragma unroll
        for (int mt = 0; mt < 4; ++mt) {
            bf16x8 xf = ld8(xs, 16 * mt + c0, (32 * ks + 8 * g) * 2);
            acc[0][mt] = MFMA16(w0, xf, acc[0][mt]);   // D[dh 0-15][tok]
            acc[1][mt] = MFMA16(w1, xf, acc[1][mt]);   // D[dh 16-31][tok]
        }
    }
    float4 b0 = *(const float4*)(biasp + rowbase + 4 * g);
    float4 b1 = *(const float4*)(biasp + rowbase + 16 + 4 * g);
    #pragma unroll
    for (int t = 0; t < 4; ++t) {
        out[t] = redist4(
            pack2((acc[0][t][0] + b0.x) * scale, (acc[0][t][1] + b0.y) * scale),
            pack2((acc[0][t][2] + b0.z) * scale, (acc[0][t][3] + b0.w) * scale),
            pack2((acc[1][t][0] + b1.x) * scale, (acc[1][t][1] + b1.y) * scale),
            pack2((acc[1][t][2] + b1.z) * scale, (acc[1][t][3] + b1.w) * scale),
            gl, gh);
    }
}

template<int USEB>
__global__ __launch_bounds__(256, 4) void winattn_kernel(
    const float* __restrict__ xg, const float* __restrict__ maskg,
    const float* __restrict__ qwg, const float* __restrict__ qbg,
    const float* __restrict__ pwg, const float* __restrict__ pbg,
    const bf16_t* __restrict__ wqb, const bf16_t* __restrict__ wpb,
    const int nW, float* __restrict__ outg)
{
    __shared__ char xs[17408];   // x, later att

    const int b    = blockIdx.x;
    const int tid  = threadIdx.x;
    const int w    = tid >> 6;       // wave 0..3 == head
    const int lane = tid & 63;
    const int g    = lane >> 4;
    const int c0   = lane & 15;
    const bool gl  = (g & 1) != 0, gh = (g & 2) != 0;
    const int h    = w;

    // ---- stage x (49x128 f32 -> bf16 LDS); zero rows 49..63 ----
    {
        const float4* xb = (const float4*)(xg + (long)b * 6272);
        #pragma unroll
        for (int it = 0; it < 7; ++it) {
            int i = tid + it * 256;
            if (i < 1568) {
                float4 f = xb[i];
                int row = i >> 5, colb = (i & 31) << 3;
                bf16x4 hq;
                hq[0] = (bf16_t)f.x; hq[1] = (bf16_t)f.y; hq[2] = (bf16_t)f.z; hq[3] = (bf16_t)f.w;
                st4(xs, row, colb, hq);
            }
        }
        #pragma unroll
        for (int it = 0; it < 4; ++it) {        // 15 rows x 64 words = 960
            int i = tid + it * 256;
            if (i < 960) {
                int row = 49 + (i >> 6), byteo = (i & 63) << 2;
                *(u32*)(xs + row * ROWB + byteo) = 0u;
            }
        }
    }
    __syncthreads();   // b1: x staged

    // ---- QKV, all in registers (one head per wave) ----
    const float qs = 0.17677669529663687f;   // 32^-0.5
    bf16x8 qfr[4], ka[4];
    pass_rowmajor<USEB>(xs, qwg, wqb, 32 * h,       qbg, qs,  g, c0, gl, gh, qfr);
    pass_rowmajor<USEB>(xs, qwg, wqb, 128 + 32 * h, qbg, 1.f, g, c0, gl, gh, ka);

    // V pass: D[tok][dh], redist merges tok-tiles -> va[fi][kt] = vT[16fi+c0][32kt+8g+i]
    bf16x8 va[2][2];
    {
        const int rb = 256 + 32 * h;
        f32x4 acc[4][2];
        #pragma unroll
        for (int mt = 0; mt < 4; ++mt)
            #pragma unroll
            for (int d = 0; d < 2; ++d) acc[mt][d] = {0.f, 0.f, 0.f, 0.f};
        #pragma unroll
        for (int ks = 0; ks < 4; ++ks) {
            bf16x8 w0 = ldw<USEB>(qwg, wqb, (rb + c0) * 128 + 32 * ks + 8 * g);
            bf16x8 w1 = ldw<USEB>(qwg, wqb, (rb + 16 + c0) * 128 + 32 * ks + 8 * g);
            #pragma unroll
            for (int mt = 0; mt < 4; ++mt) {
                bf16x8 xf = ld8(xs, 16 * mt + c0, (32 * ks + 8 * g) * 2);
                acc[mt][0] = MFMA16(xf, w0, acc[mt][0]);   // D[tok][dh 0-15]
                acc[mt][1] = MFMA16(xf, w1, acc[mt][1]);   // D[tok][dh 16-31]
            }
        }
        float vb0 = qbg[rb + c0];
        float vb1 = qbg[rb + 16 + c0];
        #pragma unroll
        for (int kt = 0; kt < 2; ++kt) {
            va[0][kt] = redist4(
                pack2(acc[2 * kt][0][0] + vb0, acc[2 * kt][0][1] + vb0),
                pack2(acc[2 * kt][0][2] + vb0, acc[2 * kt][0][3] + vb0),
                pack2(acc[2 * kt + 1][0][0] + vb0, acc[2 * kt + 1][0][1] + vb0),
                pack2(acc[2 * kt + 1][0][2] + vb0, acc[2 * kt + 1][0][3] + vb0),
                gl, gh);
            va[1][kt] = redist4(
                pack2(acc[2 * kt][1][0] + vb1, acc[2 * kt][1][1] + vb1),
                pack2(acc[2 * kt][1][2] + vb1, acc[2 * kt][1][3] + vb1),
                pack2(acc[2 * kt + 1][1][0] + vb1, acc[2 * kt + 1][1][1] + vb1),
                pack2(acc[2 * kt + 1][1][2] + vb1, acc[2 * kt + 1][1][3] + vb1),
                gl, gh);
        }
    }
    __syncthreads();   // b1.5: all x reads done -> att may overwrite

    // ---- attention per 16-q-tile: S^T -> softmax -> redist P -> PV -> att ----
    const float* mrow = maskg + (long)(b % nW) * 2401;
    #pragma unroll
    for (int nt = 0; nt < 4; ++nt) {
        f32x4 s[4];
        #pragma unroll
        for (int kt = 0; kt < 4; ++kt) s[kt] = {0.f, 0.f, 0.f, 0.f};
        #pragma unroll
        for (int kt = 0; kt < 4; ++kt)
            s[kt] = MFMA16(ka[kt], qfr[nt], s[kt]);   // D[kv][q]: kv=16kt+4g+r, q=16nt+c0

        // fold mask in place (kv tile 3: only kv=48 valid, g==0 r==0)
        {
            int q  = 16 * nt + c0;
            int qm = q < 49 ? q : 48;
            const float* mr = mrow + qm * 49;
            f32x4u m0 = *(const f32x4u*)(mr + 4 * g);
            f32x4u m1 = *(const f32x4u*)(mr + 16 + 4 * g);
            f32x4u m2 = *(const f32x4u*)(mr + 32 + 4 * g);
            float m48 = mr[48];
            #pragma unroll
            for (int r = 0; r < 4; ++r) {
                s[0][r] += m0[r]; s[1][r] += m1[r]; s[2][r] += m2[r];
            }
            s[3][0] = (g == 0) ? s[3][0] + m48 : -1e30f;
            s[3][1] = -1e30f; s[3][2] = -1e30f; s[3][3] = -1e30f;
        }

        float mx = -1e30f;
        #pragma unroll
        for (int kt = 0; kt < 4; ++kt)
            #pragma unroll
            for (int r = 0; r < 4; ++r) mx = fmaxf(mx, s[kt][r]);
        mx = fmaxf(mx, __shfl_xor(mx, 16));
        mx = fmaxf(mx, __shfl_xor(mx, 32));

        float sum = 0.f;
        u32 wd[8];
        #pragma unroll
        for (int kt = 0; kt < 4; ++kt) {
            float e0 = __expf(s[kt][0] - mx), e1 = __expf(s[kt][1] - mx);
            float e2 = __expf(s[kt][2] - mx), e3 = __expf(s[kt][3] - mx);
            sum += (e0 + e1) + (e2 + e3);
            wd[2 * kt]     = pack2(e0, e1);
            wd[2 * kt + 1] = pack2(e2, e3);
        }
        sum += __shfl_xor(sum, 16);
        sum += __shfl_xor(sum, 32);
        float inv = 1.f / sum;   // uniform within the 4-lane c0-column

        bf16x8 pa0 = redist4(wd[0], wd[1], wd[2], wd[3], gl, gh);
        bf16x8 pa1 = redist4(wd[4], wd[5], wd[6], wd[7], gl, gh);

        f32x4 oo[2];
        oo[0] = {0.f, 0.f, 0.f, 0.f}; oo[1] = {0.f, 0.f, 0.f, 0.f};
        oo[0] = MFMA16(va[0][0], pa0, oo[0]);
        oo[0] = MFMA16(va[0][1], pa1, oo[0]);   // D[dh 0-15][q]
        oo[1] = MFMA16(va[1][0], pa0, oo[1]);
        oo[1] = MFMA16(va[1][1], pa1, oo[1]);   // D[dh 16-31][q]

        int q = 16 * nt + c0;
        #pragma unroll
        for (int dt = 0; dt < 2; ++dt) {
            bf16x4 t;
            t[0] = (bf16_t)(oo[dt][0] * inv); t[1] = (bf16_t)(oo[dt][1] * inv);
            t[2] = (bf16_t)(oo[dt][2] * inv); t[3] = (bf16_t)(oo[dt][3] * inv);
            st4(xs, q, (32 * h + 16 * dt + 4 * g) * 2, t);   // att[q][c]
        }
    }
    __syncthreads();   // b2: att complete

    // ---- proj GEMM: D[col][tok] = Wp*att^T; wave owns cols 32w..32w+31 ----
    {
        f32x4 acc[2][4];
        #pragma unroll
        for (int nt = 0; nt < 2; ++nt)
            #pragma unroll
            for (int mt = 0; mt < 4; ++mt) acc[nt][mt] = {0.f, 0.f, 0.f, 0.f};
        #pragma unroll
        for (int ks = 0; ks < 4; ++ks) {
            bf16x8 p0 = ldw<USEB>(pwg, wpb, (32 * w + c0) * 128 + 32 * ks + 8 * g);
            bf16x8 p1 = ldw<USEB>(pwg, wpb, (32 * w + 16 + c0) * 128 + 32 * ks + 8 * g);
            #pragma unroll
            for (int mt = 0; mt < 4; ++mt) {
                bf16x8 af = ld8(xs, 16 * mt + c0, (32 * ks + 8 * g) * 2);
                acc[0][mt] = MFMA16(p0, af, acc[0][mt]);
                acc[1][mt] = MFMA16(p1, af, acc[1][mt]);
            }
        }
        float4 pb0 = *(const float4*)(pbg + 32 * w + 4 * g);
        float4 pb1 = *(const float4*)(pbg + 32 * w + 16 + 4 * g);
        float* ob = outg + (long)b * 6272;
        #pragma unroll
        for (int nt = 0; nt < 2; ++nt) {
            float4 pb = nt ? pb1 : pb0;
            #pragma unroll
            for (int mt = 0; mt < 4; ++mt) {
                int tok = 16 * mt + c0;
                if (tok < 49) {
                    float4 t;
                    t.x = acc[nt][mt][0] + pb.x;
                    t.y = acc[nt][mt][1] + pb.y;
                    t.z = acc[nt][mt][2] + pb.z;
                    t.w = acc[nt][mt][3] + pb.w;
                    *(float4*)(ob + tok * 128 + 32 * w + 16 * nt + 4 * g) = t;
                }
            }
        }
    }
}

extern "C" void kernel_launch(void* const* d_in, const int* in_sizes, int n_in,
                              void* d_out, int out_size, void* d_ws, size_t ws_size,
                              hipStream_t stream) {
    const float* xg  = (const float*)d_in[0];
    const float* mg  = (const float*)d_in[1];
    const float* qwg = (const float*)d_in[2];
    const float* qbg = (const float*)d_in[3];
    const float* pwg = (const float*)d_in[4];
    const float* pbg = (const float*)d_in[5];
    float* outg = (float*)d_out;

    const int B  = in_sizes[0] / (49 * 128);   // 2048
    const int nW = in_sizes[1] / (49 * 49);    // 64

    int use_wbf = (d_ws != nullptr && ws_size >= 131072) ? 1 : 0;
    bf16_t* wqb = (bf16_t*)d_ws;
    bf16_t* wpb = use_wbf ? (wqb + 49152) : nullptr;

    if (use_wbf) {
        wconv_kernel<<<64, 256, 0, stream>>>(qwg, pwg, wqb);
        winattn_kernel<1><<<B, 256, 0, stream>>>(
            xg, mg, qwg, qbg, pwg, pbg, wqb, wpb, nW, outg);
    } else {
        winattn_kernel<0><<<B, 256, 0, stream>>>(
            xg, mg, qwg, qbg, pwg, pbg, nullptr, nullptr, nW, outg);
    }
}